// Round 11
// baseline (91.092 us; speedup 1.0000x reference)
//
#include <hip/hip_runtime.h>
#include <hip/hip_bf16.h>
#include <stdint.h>

#define DI __device__ __forceinline__

typedef __attribute__((ext_vector_type(8))) short short8;
typedef __attribute__((ext_vector_type(4))) float f32x4;

constexpr int CH   = 128;
constexpr int FH   = 120;
constexpr int FW   = 120;
constexpr int NBOX = 512;
constexpr int KDIM = 49 * 128;   // 6272
constexpr int D1   = 512;
constexpr int D2   = 256;
constexpr int SPLITS = 14;
constexpr int KC     = KDIM / SPLITS; // 448

DI float bf2f(uint32_t u16) { union { uint32_t i; float f; } v; v.i = u16 << 16; return v.f; }
DI float bf2f_hi(uint32_t u) { union { uint32_t i; float f; } v; v.i = u & 0xffff0000u; return v.f; }
DI uint16_t f2bf(float f) {
    __hip_bfloat16 h = __float2bfloat16(f);
    union { __hip_bfloat16 h; uint16_t u; } v; v.h = h; return v.u;
}

// ---------- K1: features [128,120,120] f32 -> ft [120,120,128] bf16 pairs ----------
__global__ __launch_bounds__(256) void k_preft(const float* __restrict__ f,
                                               uint32_t* __restrict__ ft) {
    __shared__ float lds[30 * 129];
    const int v = blockIdx.x, t = threadIdx.x;   // 480 blocks
    const int y = v >> 2, x0 = (v & 3) * 30;
    for (int e = t; e < 30 * 128; e += 256) {
        int c = e / 30, x = e - c * 30;
        lds[x * 129 + c] = f[c * (FH * FW) + y * FW + x0 + x];
    }
    __syncthreads();
    for (int e = t; e < 30 * 64; e += 256) {
        int x = e >> 6, cp = e & 63;
        float lo = lds[x * 129 + 2 * cp];
        float hi = lds[x * 129 + 2 * cp + 1];
        ft[(y * FW + x0 + x) * 64 + cp] = (uint32_t)f2bf(lo) | ((uint32_t)f2bf(hi) << 16);
    }
}

// ---------- K2: ROI align, block-per-box (512) + W1 transpose (784) + W2 (32) ----------
// ROI: phase 1 builds 35 y-slot + 35 x-slot tables (offset + pre-masked weight) in
// LDS once per box; phase 2: 8 waves x ~6 bins, loops only ACTIVE samples
// (gh,gw are box-uniform -> no divergence, no masked work).
__global__ __launch_bounds__(512) void k_roi_w(const uint32_t* __restrict__ ft,
                                               const float* __restrict__ boxes,
                                               const float* __restrict__ W1,
                                               const float* __restrict__ W2,
                                               uint32_t* __restrict__ A,
                                               uint16_t* __restrict__ W1rT,
                                               uint16_t* __restrict__ W2T) {
    __shared__ __align__(16) float lds[128 * 33];
    __shared__ float twf[160];   // yw_h[0..34], yw_l[40..74], xw_h[80..114], xw_l[120..154]
    __shared__ int   twi[160];   // yo0, yo1, xo0, xo1 (same strides)
    const int blk = blockIdx.x, t = threadIdx.x;
    if (blk < 512) {
#pragma clang fp contract(off)
        const int box = blk;
        const float bx = boxes[box * 4 + 0], by = boxes[box * 4 + 1];
        const float bw = boxes[box * 4 + 2], bh = boxes[box * 4 + 3];
        const float x1 = bx * 120.0f - 0.5f;
        const float y1 = by * 120.0f - 0.5f;
        const float roi_w = bw * 120.0f, roi_h = bh * 120.0f;
        const float bin_w = roi_w / 7.0f, bin_h = roi_h / 7.0f;
        const float gwf = fmaxf(ceilf(roi_w / 7.0f), 1.0f);
        const float ghf = fmaxf(ceilf(roi_h / 7.0f), 1.0f);
        const int gwi = (int)gwf, ghi = (int)ghf;

        if (t < 35) {
            const int ph = t / 5, sy = t % 5;
            float yy = (y1 + (float)ph * bin_h) + ((float)sy + 0.5f) * bin_h / ghf;
            float my = ((yy > -1.0f) && (yy < 120.0f)) ? 1.0f : 0.0f;
            float yc = fminf(fmaxf(yy, 0.0f), 119.0f);
            int y0 = (int)floorf(yc);
            int yh = min(y0 + 1, 119);
            float ly = yc - (float)y0, hy = 1.0f - ly;
            twf[t]      = hy * my;
            twf[40 + t] = ly * my;
            twi[t]      = y0 * (FW * 64);
            twi[40 + t] = yh * (FW * 64);
        } else if (t < 70) {
            const int u = t - 35;
            const int pw = u / 5, sx = u % 5;
            float xx = (x1 + (float)pw * bin_w) + ((float)sx + 0.5f) * bin_w / gwf;
            float mx = ((xx > -1.0f) && (xx < 120.0f)) ? 1.0f : 0.0f;
            float xc = fminf(fmaxf(xx, 0.0f), 119.0f);
            int x0 = (int)floorf(xc);
            int xh = min(x0 + 1, 119);
            float lx = xc - (float)x0, hx = 1.0f - lx;
            twf[80 + u]  = hx * mx;
            twf[120 + u] = lx * mx;
            twi[80 + u]  = x0 * 64;
            twi[120 + u] = xh * 64;
        }
        __syncthreads();

        const int w = t >> 6, lane = t & 63;
        const float cnt = ghf * gwf;
        for (int bin = w; bin < 49; bin += 8) {
            const int ph = bin / 7, pw = bin - ph * 7;
            float acc0 = 0.0f, acc1 = 0.0f;
            for (int sy = 0; sy < ghi; ++sy) {
                const int iy = ph * 5 + sy;
                const float wyh = twf[iy], wyl = twf[40 + iy];
                const uint32_t* r0 = ft + twi[iy] + lane;
                const uint32_t* r1 = ft + twi[40 + iy] + lane;
                for (int sx = 0; sx < gwi; ++sx) {
                    const int ix = pw * 5 + sx;
                    const float wxh = twf[80 + ix], wxl = twf[120 + ix];
                    const int o0 = twi[80 + ix], o1 = twi[120 + ix];
                    uint32_t u00 = r0[o0], u01 = r0[o1];
                    uint32_t u10 = r1[o0], u11 = r1[o1];
                    float w00 = wyh * wxh, w01 = wyh * wxl;
                    float w10 = wyl * wxh, w11 = wyl * wxl;
                    acc0 += w00 * bf2f(u00 & 0xffffu) + w01 * bf2f(u01 & 0xffffu)
                          + w10 * bf2f(u10 & 0xffffu) + w11 * bf2f(u11 & 0xffffu);
                    acc1 += w00 * bf2f_hi(u00) + w01 * bf2f_hi(u01)
                          + w10 * bf2f_hi(u10) + w11 * bf2f_hi(u11);
                }
            }
            const float v0 = acc0 / cnt, v1 = acc1 / cnt;
            A[(size_t)(box * 49 + bin) * 64 + lane] =
                (uint32_t)f2bf(v0) | ((uint32_t)f2bf(v1) << 16);
        }
    } else if (blk < 1296) {
        const int vb = blk - 512;               // 0..783
        const int b = vb % 49, j0 = (vb / 49) * 32;
        for (int e = t; e < 4096; e += 512) {
            int ci = e >> 5, jj = e & 31;
            lds[ci * 33 + jj] = W1[(ci * 49 + b) * D1 + j0 + jj];
        }
        __syncthreads();
        for (int e = t; e < 4096; e += 512) {
            int jj = e >> 7, ci = e & 127;
            W1rT[(size_t)(j0 + jj) * KDIM + b * 128 + ci] = f2bf(lds[ci * 33 + jj]);
        }
    } else {
        const int v2 = blk - 1296;              // 0..31
        const int n0 = (v2 & 7) * 32, k0 = (v2 >> 3) * 128;
        for (int e = t; e < 4096; e += 512) {
            int k = e >> 5, nn = e & 31;
            lds[k * 33 + nn] = W2[(k0 + k) * D2 + n0 + nn];
        }
        __syncthreads();
        for (int e = t; e < 4096; e += 512) {
            int nn = e >> 7, k = e & 127;
            W2T[(n0 + nn) * D1 + k0 + k] = f2bf(lds[k * 33 + nn]);
        }
    }
}

// ---------- K3: GEMM1 split-K -> Pp (proven) ----------
__global__ __launch_bounds__(256) void k_gemm1(const uint16_t* __restrict__ A,
                                               const uint16_t* __restrict__ B,
                                               float* __restrict__ P) {
    __shared__ __align__(16) uint16_t As[128 * 32];
    __shared__ __align__(16) uint16_t Bs[128 * 32];
    const int t = threadIdx.x;
    const int lane = t & 63, w = t >> 6;
    const int wr = w >> 1, wc = w & 1;
    const int m0 = blockIdx.x * 128, n0 = blockIdx.y * 128;
    const int kbase = blockIdx.z * KC;

    f32x4 acc[4][4] = {};
    const int kb = lane >> 4, r16 = lane & 15;

    for (int ks = 0; ks < KC / 32; ++ks) {
        const int kk = kbase + ks * 32;
        __syncthreads();
#pragma unroll
        for (int i = 0; i < 2; ++i) {
            int ch = t + 256 * i;
            int row = ch >> 2, c8 = ch & 3;
            int sw = (row >> 1) & 3;
            const uint16_t* ga = A + (size_t)(m0 + row) * KDIM + kk + c8 * 8;
            *(uint4*)&As[row * 32 + (c8 ^ sw) * 8] = *(const uint4*)ga;
            const uint16_t* gb = B + (size_t)(n0 + row) * KDIM + kk + c8 * 8;
            *(uint4*)&Bs[row * 32 + (c8 ^ sw) * 8] = *(const uint4*)gb;
        }
        __syncthreads();

        short8 af[4], bfr[4];
#pragma unroll
        for (int mi = 0; mi < 4; ++mi) {
            int ar = wr * 64 + mi * 16 + r16;
            af[mi] = *(const short8*)&As[ar * 32 + (kb ^ ((ar >> 1) & 3)) * 8];
        }
#pragma unroll
        for (int ni = 0; ni < 4; ++ni) {
            int br = wc * 64 + ni * 16 + r16;
            bfr[ni] = *(const short8*)&Bs[br * 32 + (kb ^ ((br >> 1) & 3)) * 8];
        }
#pragma unroll
        for (int mi = 0; mi < 4; ++mi)
#pragma unroll
            for (int ni = 0; ni < 4; ++ni)
                acc[mi][ni] = __builtin_amdgcn_mfma_f32_16x16x32_bf16(af[mi], bfr[ni], acc[mi][ni], 0, 0, 0);
    }

    float* outp = P + (size_t)blockIdx.z * (D1 * D1);
#pragma unroll
    for (int mi = 0; mi < 4; ++mi)
#pragma unroll
        for (int ni = 0; ni < 4; ++ni) {
            int row = m0 + wr * 64 + mi * 16 + kb * 4;
            int col = n0 + wc * 64 + ni * 16 + r16;
#pragma unroll
            for (int r = 0; r < 4; ++r)
                outp[(size_t)(row + r) * D1 + col] = acc[mi][ni][r];
        }
}

// ---------- K4: reduce split-K + bias + ReLU -> H bf16, full-machine grid ----------
__global__ __launch_bounds__(256) void k_reduce1(const float* __restrict__ P,
                                                 const float* __restrict__ b1,
                                                 uint16_t* __restrict__ Hm) {
    const int e4 = blockIdx.x * 256 + threadIdx.x;  // 65536 f32x4 groups
    const f32x4* P4 = (const f32x4*)P;
    f32x4 s = {};
#pragma unroll
    for (int i = 0; i < SPLITS; ++i) s += P4[(size_t)i * (D1 * D1 / 4) + e4];
    const int c4 = (e4 & 127) * 4;
    uint16_t h[4];
#pragma unroll
    for (int j = 0; j < 4; ++j) h[j] = f2bf(fmaxf(s[j] + b1[c4 + j], 0.0f));
    uint2 pk;
    pk.x = (uint32_t)h[0] | ((uint32_t)h[1] << 16);
    pk.y = (uint32_t)h[2] | ((uint32_t)h[3] << 16);
    *(uint2*)&Hm[(size_t)e4 * 4] = pk;
}

// ---------- K5: GEMM2 (proven thin version) ----------
__global__ __launch_bounds__(256) void k_gemm2(const uint16_t* __restrict__ Hm,
                                               const uint16_t* __restrict__ W2T,
                                               const float* __restrict__ b2,
                                               float* __restrict__ out) {
    const int wid  = blockIdx.x * 4 + (threadIdx.x >> 6); // 0..511
    const int lane = threadIdx.x & 63;
    const int mt = wid >> 4, nt = wid & 15;
    const int m0 = mt * 16, n0 = nt * 16;
    const int g = lane >> 4, i = lane & 15;
    f32x4 acc = {};
#pragma unroll
    for (int kk = 0; kk < D1 / 32; ++kk) {
        short8 a = *(const short8*)&Hm[(m0 + i) * D1 + kk * 32 + g * 8];
        short8 b = *(const short8*)&W2T[(n0 + i) * D1 + kk * 32 + g * 8];
        acc = __builtin_amdgcn_mfma_f32_16x16x32_bf16(a, b, acc, 0, 0, 0);
    }
    const float bias = b2[n0 + i];
#pragma unroll
    for (int r = 0; r < 4; ++r)
        out[(size_t)(m0 + g * 4 + r) * D2 + n0 + i] = acc[r] + bias;
}

extern "C" void kernel_launch(void* const* d_in, const int* in_sizes, int n_in,
                              void* d_out, int out_size, void* d_ws, size_t ws_size,
                              hipStream_t stream) {
    const float* f     = (const float*)d_in[0];
    const float* boxes = (const float*)d_in[1];
    const float* W1    = (const float*)d_in[2];
    const float* b1    = (const float*)d_in[3];
    const float* W2    = (const float*)d_in[4];
    const float* b2    = (const float*)d_in[5];
    float* out = (float*)d_out;

    char* p = (char*)d_ws;
    uint32_t* ft   = (uint32_t*)p; p += (size_t)FH * FW * (CH / 2) * 4;  // 3.7 MB
    uint16_t* W1rT = (uint16_t*)p; p += (size_t)D1 * KDIM * 2;           // 6.4 MB
    uint16_t* W2T  = (uint16_t*)p; p += (size_t)D2 * D1 * 2;             // 0.26 MB
    uint16_t* Ar   = (uint16_t*)p; p += (size_t)NBOX * KDIM * 2;         // 6.4 MB
    float*    Pp   = (float*)p;    p += (size_t)SPLITS * D1 * D1 * 4;    // 14.7 MB
    uint16_t* Hm   = (uint16_t*)p; p += (size_t)D1 * D1 * 2;             // 0.52 MB

    k_preft<<<480, 256, 0, stream>>>(f, ft);
    k_roi_w<<<1328, 512, 0, stream>>>(ft, boxes, W1, W2, (uint32_t*)Ar, W1rT, W2T);
    k_gemm1<<<dim3(4, 4, SPLITS), 256, 0, stream>>>(Ar, W1rT, Pp);
    k_reduce1<<<D1 * D1 / 4 / 256, 256, 0, stream>>>(Pp, b1, Hm);
    k_gemm2<<<(D1 / 16) * (D2 / 16) / 4, 256, 0, stream>>>(Hm, W2T, b2, out);
}

// Round 12
// 64.685 us; speedup vs baseline: 1.4082x; 1.4082x over previous
//
#include <hip/hip_runtime.h>
#include <hip/hip_bf16.h>
#include <stdint.h>

#define DI __device__ __forceinline__

typedef __attribute__((ext_vector_type(8))) short short8;
typedef __attribute__((ext_vector_type(4))) float f32x4;
typedef __attribute__((ext_vector_type(2))) float f32x2;

constexpr int CH   = 128;
constexpr int FH   = 120;
constexpr int FW   = 120;
constexpr int NBOX = 512;
constexpr int KDIM = 49 * 128;   // 6272
constexpr int D1   = 512;
constexpr int D2   = 256;
constexpr int SPLITS = 14;
constexpr int KC     = KDIM / SPLITS; // 448

DI float bf2f(uint32_t u16) { union { uint32_t i; float f; } v; v.i = u16 << 16; return v.f; }
DI float bf2f_hi(uint32_t u) { union { uint32_t i; float f; } v; v.i = u & 0xffff0000u; return v.f; }
DI uint16_t f2bf(float f) {
    __hip_bfloat16 h = __float2bfloat16(f);
    union { __hip_bfloat16 h; uint16_t u; } v; v.h = h; return v.u;
}
DI f32x2 sp2(float s) { f32x2 r; r.x = s; r.y = s; return r; }

// ---------- K1: features [128,120,120] f32 -> ft [120,120,128] bf16 pairs ----------
__global__ __launch_bounds__(256) void k_preft(const float* __restrict__ f,
                                               uint32_t* __restrict__ ft) {
    __shared__ float lds[30 * 129];
    const int v = blockIdx.x, t = threadIdx.x;   // 480 blocks
    const int y = v >> 2, x0 = (v & 3) * 30;
    for (int e = t; e < 30 * 128; e += 256) {
        int c = e / 30, x = e - c * 30;
        lds[x * 129 + c] = f[c * (FH * FW) + y * FW + x0 + x];
    }
    __syncthreads();
    for (int e = t; e < 30 * 64; e += 256) {
        int x = e >> 6, cp = e & 63;
        float lo = lds[x * 129 + 2 * cp];
        float hi = lds[x * 129 + 2 * cp + 1];
        ft[(y * FW + x0 + x) * 64 + cp] = (uint32_t)f2bf(lo) | ((uint32_t)f2bf(hi) << 16);
    }
}

// ---------- ROI body: exact-GW static unroll (bit-identical math to R8/R9) ----------
template<int GW>
DI void roi_body(const uint32_t* __restrict__ ft, uint32_t* __restrict__ A,
                 int wid, int lane, float xbase, float bin_w, float gwf,
                 float ybase, float bin_h, float ghf, int ghi, float cnt) {
#pragma clang fp contract(off)
    int offx0[GW], offxh[GW];
    float hxm[GW], lxm[GW];
#pragma unroll
    for (int j = 0; j < GW; ++j) {
        float xx = xbase + ((float)j + 0.5f) * bin_w / gwf;
        bool vx = (xx > -1.0f) && (xx < 120.0f);
        float xc = fminf(fmaxf(xx, 0.0f), 119.0f);
        int x0 = (int)floorf(xc);
        int xh = min(x0 + 1, 119);
        float lx = xc - (float)x0, hx = 1.0f - lx;
        float mx = vx ? 1.0f : 0.0f;
        hxm[j] = hx * mx; lxm[j] = lx * mx;
        offx0[j] = x0 * 64; offxh[j] = xh * 64;
    }

    f32x2 acc = {0.0f, 0.0f};
    for (int sy = 0; sy < ghi; ++sy) {
        float yy = ybase + ((float)sy + 0.5f) * bin_h / ghf;
        float my = ((yy > -1.0f) && (yy < 120.0f)) ? 1.0f : 0.0f;
        float yc = fminf(fmaxf(yy, 0.0f), 119.0f);
        int y0 = (int)floorf(yc);
        int yh = min(y0 + 1, 119);
        float ly = yc - (float)y0, hy = 1.0f - ly;
        float hym = hy * my, lym = ly * my;
        const uint32_t* r0 = ft + (size_t)(y0 * (FW * 64)) + lane;
        const uint32_t* r1 = ft + (size_t)(yh * (FW * 64)) + lane;
        uint32_t u00[GW], u01[GW], u10[GW], u11[GW];
#pragma unroll
        for (int j = 0; j < GW; ++j) {
            u00[j] = r0[offx0[j]];
            u01[j] = r0[offxh[j]];
            u10[j] = r1[offx0[j]];
            u11[j] = r1[offxh[j]];
        }
#pragma unroll
        for (int j = 0; j < GW; ++j) {
            float w00 = hym * hxm[j], w01 = hym * lxm[j];
            float w10 = lym * hxm[j], w11 = lym * lxm[j];
            f32x2 v00 = {bf2f(u00[j] & 0xffffu), bf2f_hi(u00[j])};
            f32x2 v01 = {bf2f(u01[j] & 0xffffu), bf2f_hi(u01[j])};
            f32x2 v10 = {bf2f(u10[j] & 0xffffu), bf2f_hi(u10[j])};
            f32x2 v11 = {bf2f(u11[j] & 0xffffu), bf2f_hi(u11[j])};
            acc += sp2(w00) * v00 + sp2(w01) * v01 + sp2(w10) * v10 + sp2(w11) * v11;
        }
    }
    const float v0 = acc.x / cnt, v1 = acc.y / cnt;
    A[(size_t)wid * 64 + lane] = (uint32_t)f2bf(v0) | ((uint32_t)f2bf(v1) << 16);
}

// ---------- K2: ROI align (6272 blk, wave per box-bin) + W1 (784) + W2 (32) ----------
__global__ __launch_bounds__(256) void k_roi_w(const uint32_t* __restrict__ ft,
                                               const float* __restrict__ boxes,
                                               const float* __restrict__ W1,
                                               const float* __restrict__ W2,
                                               uint32_t* __restrict__ A,
                                               uint16_t* __restrict__ W1rT,
                                               uint16_t* __restrict__ W2T) {
    __shared__ __align__(16) float lds[128 * 33];
    const int blk = blockIdx.x, t = threadIdx.x;
    if (blk < 6272) {
#pragma clang fp contract(off)
        const int wid  = (blk << 2) + (t >> 6); // 0..25087
        const int lane = t & 63;
        const int box = wid / 49, bin = wid % 49;
        const int ph = bin / 7, pw = bin % 7;

        const float bx = boxes[box * 4 + 0], by = boxes[box * 4 + 1];
        const float bw = boxes[box * 4 + 2], bh = boxes[box * 4 + 3];
        const float x1 = bx * 120.0f - 0.5f;
        const float y1 = by * 120.0f - 0.5f;
        const float roi_w = bw * 120.0f, roi_h = bh * 120.0f;
        const float bin_w = roi_w / 7.0f, bin_h = roi_h / 7.0f;
        const float gwf = fmaxf(ceilf(roi_w / 7.0f), 1.0f);
        const float ghf = fmaxf(ceilf(roi_h / 7.0f), 1.0f);
        const int gwi = (int)gwf, ghi = (int)ghf;
        const float ybase = y1 + (float)ph * bin_h;
        const float xbase = x1 + (float)pw * bin_w;
        const float cnt = ghf * gwf;

        switch (gwi) {
        case 1: roi_body<1>(ft, A, wid, lane, xbase, bin_w, gwf, ybase, bin_h, ghf, ghi, cnt); break;
        case 2: roi_body<2>(ft, A, wid, lane, xbase, bin_w, gwf, ybase, bin_h, ghf, ghi, cnt); break;
        case 3: roi_body<3>(ft, A, wid, lane, xbase, bin_w, gwf, ybase, bin_h, ghf, ghi, cnt); break;
        case 4: roi_body<4>(ft, A, wid, lane, xbase, bin_w, gwf, ybase, bin_h, ghf, ghi, cnt); break;
        default: roi_body<5>(ft, A, wid, lane, xbase, bin_w, gwf, ybase, bin_h, ghf, ghi, cnt); break;
        }
    } else if (blk < 7056) {
        const int vb = blk - 6272;              // 0..783
        const int b = vb % 49, j0 = (vb / 49) * 32;
        for (int e = t; e < 4096; e += 256) {
            int ci = e >> 5, jj = e & 31;
            lds[ci * 33 + jj] = W1[(ci * 49 + b) * D1 + j0 + jj];
        }
        __syncthreads();
        for (int e = t; e < 4096; e += 256) {
            int jj = e >> 7, ci = e & 127;
            W1rT[(size_t)(j0 + jj) * KDIM + b * 128 + ci] = f2bf(lds[ci * 33 + jj]);
        }
    } else {
        const int v2 = blk - 7056;              // 0..31
        const int n0 = (v2 & 7) * 32, k0 = (v2 >> 3) * 128;
        for (int e = t; e < 4096; e += 256) {
            int k = e >> 5, nn = e & 31;
            lds[k * 33 + nn] = W2[(k0 + k) * D2 + n0 + nn];
        }
        __syncthreads();
        for (int e = t; e < 4096; e += 256) {
            int nn = e >> 7, k = e & 127;
            W2T[(n0 + nn) * D1 + k0 + k] = f2bf(lds[k * 33 + nn]);
        }
    }
}

// ---------- K3: GEMM1 split-K -> Pp (proven) ----------
__global__ __launch_bounds__(256) void k_gemm1(const uint16_t* __restrict__ A,
                                               const uint16_t* __restrict__ B,
                                               float* __restrict__ P) {
    __shared__ __align__(16) uint16_t As[128 * 32];
    __shared__ __align__(16) uint16_t Bs[128 * 32];
    const int t = threadIdx.x;
    const int lane = t & 63, w = t >> 6;
    const int wr = w >> 1, wc = w & 1;
    const int m0 = blockIdx.x * 128, n0 = blockIdx.y * 128;
    const int kbase = blockIdx.z * KC;

    f32x4 acc[4][4] = {};
    const int kb = lane >> 4, r16 = lane & 15;

    for (int ks = 0; ks < KC / 32; ++ks) {
        const int kk = kbase + ks * 32;
        __syncthreads();
#pragma unroll
        for (int i = 0; i < 2; ++i) {
            int ch = t + 256 * i;
            int row = ch >> 2, c8 = ch & 3;
            int sw = (row >> 1) & 3;
            const uint16_t* ga = A + (size_t)(m0 + row) * KDIM + kk + c8 * 8;
            *(uint4*)&As[row * 32 + (c8 ^ sw) * 8] = *(const uint4*)ga;
            const uint16_t* gb = B + (size_t)(n0 + row) * KDIM + kk + c8 * 8;
            *(uint4*)&Bs[row * 32 + (c8 ^ sw) * 8] = *(const uint4*)gb;
        }
        __syncthreads();

        short8 af[4], bfr[4];
#pragma unroll
        for (int mi = 0; mi < 4; ++mi) {
            int ar = wr * 64 + mi * 16 + r16;
            af[mi] = *(const short8*)&As[ar * 32 + (kb ^ ((ar >> 1) & 3)) * 8];
        }
#pragma unroll
        for (int ni = 0; ni < 4; ++ni) {
            int br = wc * 64 + ni * 16 + r16;
            bfr[ni] = *(const short8*)&Bs[br * 32 + (kb ^ ((br >> 1) & 3)) * 8];
        }
#pragma unroll
        for (int mi = 0; mi < 4; ++mi)
#pragma unroll
            for (int ni = 0; ni < 4; ++ni)
                acc[mi][ni] = __builtin_amdgcn_mfma_f32_16x16x32_bf16(af[mi], bfr[ni], acc[mi][ni], 0, 0, 0);
    }

    float* outp = P + (size_t)blockIdx.z * (D1 * D1);
#pragma unroll
    for (int mi = 0; mi < 4; ++mi)
#pragma unroll
        for (int ni = 0; ni < 4; ++ni) {
            int row = m0 + wr * 64 + mi * 16 + kb * 4;
            int col = n0 + wc * 64 + ni * 16 + r16;
#pragma unroll
            for (int r = 0; r < 4; ++r)
                outp[(size_t)(row + r) * D1 + col] = acc[mi][ni][r];
        }
}

// ---------- K4: reduce split-K + bias + ReLU -> H bf16, full-machine grid ----------
__global__ __launch_bounds__(256) void k_reduce1(const float* __restrict__ P,
                                                 const float* __restrict__ b1,
                                                 uint16_t* __restrict__ Hm) {
    const int e4 = blockIdx.x * 256 + threadIdx.x;  // 65536 f32x4 groups
    const f32x4* P4 = (const f32x4*)P;
    f32x4 s = {};
#pragma unroll
    for (int i = 0; i < SPLITS; ++i) s += P4[(size_t)i * (D1 * D1 / 4) + e4];
    const int c4 = (e4 & 127) * 4;
    uint16_t h[4];
#pragma unroll
    for (int j = 0; j < 4; ++j) h[j] = f2bf(fmaxf(s[j] + b1[c4 + j], 0.0f));
    uint2 pk;
    pk.x = (uint32_t)h[0] | ((uint32_t)h[1] << 16);
    pk.y = (uint32_t)h[2] | ((uint32_t)h[3] << 16);
    *(uint2*)&Hm[(size_t)e4 * 4] = pk;
}

// ---------- K5: GEMM2 (proven thin version) ----------
__global__ __launch_bounds__(256) void k_gemm2(const uint16_t* __restrict__ Hm,
                                               const uint16_t* __restrict__ W2T,
                                               const float* __restrict__ b2,
                                               float* __restrict__ out) {
    const int wid  = blockIdx.x * 4 + (threadIdx.x >> 6); // 0..511
    const int lane = threadIdx.x & 63;
    const int mt = wid >> 4, nt = wid & 15;
    const int m0 = mt * 16, n0 = nt * 16;
    const int g = lane >> 4, i = lane & 15;
    f32x4 acc = {};
#pragma unroll
    for (int kk = 0; kk < D1 / 32; ++kk) {
        short8 a = *(const short8*)&Hm[(m0 + i) * D1 + kk * 32 + g * 8];
        short8 b = *(const short8*)&W2T[(n0 + i) * D1 + kk * 32 + g * 8];
        acc = __builtin_amdgcn_mfma_f32_16x16x32_bf16(a, b, acc, 0, 0, 0);
    }
    const float bias = b2[n0 + i];
#pragma unroll
    for (int r = 0; r < 4; ++r)
        out[(size_t)(m0 + g * 4 + r) * D2 + n0 + i] = acc[r] + bias;
}

extern "C" void kernel_launch(void* const* d_in, const int* in_sizes, int n_in,
                              void* d_out, int out_size, void* d_ws, size_t ws_size,
                              hipStream_t stream) {
    const float* f     = (const float*)d_in[0];
    const float* boxes = (const float*)d_in[1];
    const float* W1    = (const float*)d_in[2];
    const float* b1    = (const float*)d_in[3];
    const float* W2    = (const float*)d_in[4];
    const float* b2    = (const float*)d_in[5];
    float* out = (float*)d_out;

    char* p = (char*)d_ws;
    uint32_t* ft   = (uint32_t*)p; p += (size_t)FH * FW * (CH / 2) * 4;  // 3.7 MB
    uint16_t* W1rT = (uint16_t*)p; p += (size_t)D1 * KDIM * 2;           // 6.4 MB
    uint16_t* W2T  = (uint16_t*)p; p += (size_t)D2 * D1 * 2;             // 0.26 MB
    uint16_t* Ar   = (uint16_t*)p; p += (size_t)NBOX * KDIM * 2;         // 6.4 MB
    float*    Pp   = (float*)p;    p += (size_t)SPLITS * D1 * D1 * 4;    // 14.7 MB
    uint16_t* Hm   = (uint16_t*)p; p += (size_t)D1 * D1 * 2;             // 0.52 MB

    k_preft<<<480, 256, 0, stream>>>(f, ft);
    k_roi_w<<<7088, 256, 0, stream>>>(ft, boxes, W1, W2, (uint32_t*)Ar, W1rT, W2T);
    k_gemm1<<<dim3(4, 4, SPLITS), 256, 0, stream>>>(Ar, W1rT, Pp);
    k_reduce1<<<D1 * D1 / 4 / 256, 256, 0, stream>>>(Pp, b1, Hm);
    k_gemm2<<<(D1 / 16) * (D2 / 16) / 4, 256, 0, stream>>>(Hm, W2T, b2, out);
}